// Round 1
// 298.088 us; speedup vs baseline: 1.0628x; 1.0628x over previous
//
#include <hip/hip_runtime.h>
#include <math.h>

#define T_ 256
#define B_ 128
#define D_ 1024
#define K_ 21
#define NB3 43  // ceil(B_/3) wave-blocks for each scan flavor

typedef short v8s __attribute__((ext_vector_type(8)));
typedef float v4f __attribute__((ext_vector_type(4)));

__device__ __forceinline__ short bf16rne(float f) {
  unsigned u = __float_as_uint(f);
  u += 0x7FFFu + ((u >> 16) & 1u);  // round-nearest-even
  return (short)(u >> 16);
}
__device__ __forceinline__ float rdl(float v, int l) {
  return __int_as_float(__builtin_amdgcn_readlane(__float_as_int(v), l));
}

// ---------------------------------------------------------------------------
// Kernel 1: FC as bf16 MFMA GEMM (unchanged). Block = 256 thr (4 waves);
// wave wv owns k-chunk [wv*256, +256) for rows [blockIdx.x*64, +64).
// ---------------------------------------------------------------------------
__global__ __launch_bounds__(256) void fc_kernel(
    const float* __restrict__ A, const float* __restrict__ W,
    const float* __restrict__ bias, float* __restrict__ fc) {
  __shared__ float red[3][64][22];
  const int lane = threadIdx.x & 63;
  const int wv = threadIdx.x >> 6;
  const int m15 = lane & 15, g4 = lane >> 4;
  const int rowbase = blockIdx.x * 64;
  const int kc = wv * 256;
  const int n1 = 16 + m15;

  v8s bf[8][2];
#pragma unroll
  for (int s = 0; s < 8; ++s) {
    const float* Wp = W + (size_t)(kc + 32 * s + 8 * g4) * K_;
#pragma unroll
    for (int j = 0; j < 8; ++j) bf[s][0][j] = bf16rne(Wp[j * K_ + m15]);
    if (n1 < K_) {
#pragma unroll
      for (int j = 0; j < 8; ++j) bf[s][1][j] = bf16rne(Wp[j * K_ + n1]);
    } else {
#pragma unroll
      for (int j = 0; j < 8; ++j) bf[s][1][j] = 0;
    }
  }

  v4f acc[4][2];
#pragma unroll
  for (int m = 0; m < 4; ++m) {
    acc[m][0] = (v4f)(0.f);
    acc[m][1] = (v4f)(0.f);
  }

#pragma unroll
  for (int s = 0; s < 8; ++s) {
    v8s av[4];
#pragma unroll
    for (int m = 0; m < 4; ++m) {
      const float* Ap =
          A + (size_t)(rowbase + 16 * m + m15) * D_ + kc + 32 * s + 8 * g4;
      const float4 x = *(const float4*)Ap;
      const float4 y = *(const float4*)(Ap + 4);
      av[m][0] = bf16rne(x.x); av[m][1] = bf16rne(x.y);
      av[m][2] = bf16rne(x.z); av[m][3] = bf16rne(x.w);
      av[m][4] = bf16rne(y.x); av[m][5] = bf16rne(y.y);
      av[m][6] = bf16rne(y.z); av[m][7] = bf16rne(y.w);
    }
#pragma unroll
    for (int m = 0; m < 4; ++m) {
      acc[m][0] = __builtin_amdgcn_mfma_f32_16x16x32_bf16(av[m], bf[s][0],
                                                          acc[m][0], 0, 0, 0);
      acc[m][1] = __builtin_amdgcn_mfma_f32_16x16x32_bf16(av[m], bf[s][1],
                                                          acc[m][1], 0, 0, 0);
    }
  }

  if (wv > 0) {
#pragma unroll
    for (int m = 0; m < 4; ++m)
#pragma unroll
      for (int ri = 0; ri < 4; ++ri) {
        const int rl = 16 * m + 4 * g4 + ri;
        red[wv - 1][rl][m15] = acc[m][0][ri];
        if (n1 < K_) red[wv - 1][rl][n1] = acc[m][1][ri];
      }
  }
  __syncthreads();
  if (wv == 0) {
    const float b0 = bias[m15];
    const float b1 = (n1 < K_) ? bias[n1] : 0.f;
#pragma unroll
    for (int m = 0; m < 4; ++m)
#pragma unroll
      for (int ri = 0; ri < 4; ++ri) {
        const int rl = 16 * m + 4 * g4 + ri;
        float* o = fc + (size_t)(rowbase + rl) * K_;
        o[m15] = acc[m][0][ri] + red[0][rl][m15] + red[1][rl][m15] +
                 red[2][rl][m15] + b0;
        if (n1 < K_)
          o[n1] = acc[m][1][ri] + red[0][rl][n1] + red[1][rl][n1] +
                  red[2][rl][n1] + b1;
      }
  }
}

// ---------------------------------------------------------------------------
// Kernel 2: sequential scans. 3 batches per wave, lane = g*21 + jloc.
// v2: the per-step 21-lane all-gather is done through an LDS state vector:
// 1 ds_write_b32 (own value) + 5 ds_read_b128 + 1 ds_read_b32 per step
// (7 in-order DS ops vs 22 bpermutes). Per-wave LDS ops complete in order,
// so no barrier is needed for the write->read RAW. Group stride = 24 floats
// puts the 3 groups' b128 reads on disjoint bank quadruples (conflict-free
// broadcast). Each lane holds the straight (unrotated) trans column in 21
// VGPRs. The fwd renorm reuses the just-read OLD p[0] (group-uniform) as
// the scale factor -> no extra cross-lane op. Viterbi backpointers widen to
// ushort so the per-step store is 2 lanes/dword (conflict-free).
// Blocks [0,43): forward; [43,86): Viterbi; [86,214): numerator.
// ---------------------------------------------------------------------------
__global__ __launch_bounds__(64) void scan_kernel(
    const float* __restrict__ fc, const int* __restrict__ tags,
    const float* __restrict__ startT, const float* __restrict__ endT,
    const float* __restrict__ trans, float* __restrict__ out_tags,
    float* __restrict__ out_loss) {
  __shared__ unsigned short bp[256 * 66];  // bp[t][g][tag], stride 66/22
  __shared__ unsigned char h2[127 * 66];   // tag@2v   <- tag@(2v+2)
  __shared__ unsigned char h4[63 * 66];    // tag@4w   <- tag@(4w+4)
  __shared__ unsigned char cur[3 * 256];
  __shared__ v4f statev[18];               // 3 groups x 24 floats (21 + pad)

  const int lane = threadIdx.x;
  const int blk = blockIdx.x;

  if (blk < 2 * NB3) {
    const bool fwd = blk < NB3;
    const int bblk = fwd ? blk : blk - NB3;
    int g = lane / 21;
    if (g > 2) g = 2;
    int jloc = lane - g * 21;
    if (jloc > 20) jloc = 20;
    int batch = bblk * 3 + g;
    if (batch >= B_) batch = B_ - 1;

    // lengths per group (uniform, via ballots); mask[t] == (t < len)
    int len0 = 0, len1 = 0, len2 = 0;
#pragma unroll
    for (int q = 0; q < 4; ++q) {
      const int t = q * 64 + lane;
      int b0 = bblk * 3, b1 = bblk * 3 + 1, b2 = bblk * 3 + 2;
      if (b1 >= B_) b1 = B_ - 1;
      if (b2 >= B_) b2 = B_ - 1;
      len0 += __popcll(__ballot(tags[t * B_ + b0] != 0));
      len1 += __popcll(__ballot(tags[t * B_ + b1] != 0));
      len2 += __popcll(__ballot(tags[t * B_ + b2] != 0));
    }
    const int mylen = (g == 0) ? len0 : (g == 1) ? len1 : len2;

    float* sb = (float*)statev + g * 24;   // this group's state (21 floats)
    const v4f* sv = (const v4f*)sb;        // 16B-aligned (24 floats = 96B)
    const float em0 = fc[(size_t)batch * K_ + jloc];

    if (fwd) {
      // ---------------- forward / denominator (linear domain) ------------
      float ec[21];  // exp(trans[:, jloc]) straight (no rotation)
#pragma unroll
      for (int i = 0; i < K_; ++i) ec[i] = __expf(trans[i * K_ + jloc]);
      float p = __expf(startT[jloc] + em0);
      sb[jloc] = p;  // lane 63 duplicates lane 62's write (same value)
      float L = 0.f;
      float vt1 = fc[((size_t)1 * B_ + batch) * K_ + jloc];
      float vt2 = fc[((size_t)2 * B_ + batch) * K_ + jloc];
      float ee = __expf(vt1);

      for (int t = 1; t < T_; ++t) {
        // gather old state vector: 5 x ds_read_b128 + 1 x ds_read_b32,
        // in-order behind previous iteration's ds_write (no barrier needed)
        const v4f A0 = sv[0], A1 = sv[1], A2 = sv[2], A3 = sv[3], A4 = sv[4];
        const float A5 = sb[20];
        const float eet = ee;
        ee = __expf(vt2);  // exp for t+1, off critical path
        const int tn = (t + 2 < T_) ? t + 2 : T_ - 1;
        vt2 = fc[((size_t)tn * B_ + batch) * K_ + jloc];

        float d0 = A0[0] * ec[0], d1 = A0[1] * ec[1], d2 = A0[2] * ec[2];
        d0 = fmaf(A0[3], ec[3], d0); d1 = fmaf(A1[0], ec[4], d1); d2 = fmaf(A1[1], ec[5], d2);
        d0 = fmaf(A1[2], ec[6], d0); d1 = fmaf(A1[3], ec[7], d1); d2 = fmaf(A2[0], ec[8], d2);
        d0 = fmaf(A2[1], ec[9], d0); d1 = fmaf(A2[2], ec[10], d1); d2 = fmaf(A2[3], ec[11], d2);
        d0 = fmaf(A3[0], ec[12], d0); d1 = fmaf(A3[1], ec[13], d1); d2 = fmaf(A3[2], ec[14], d2);
        d0 = fmaf(A3[3], ec[15], d0); d1 = fmaf(A4[0], ec[16], d1); d2 = fmaf(A4[1], ec[17], d2);
        d0 = fmaf(A4[2], ec[18], d0); d1 = fmaf(A4[3], ec[19], d1); d2 = fmaf(A5, ec[20], d2);

        const float pn = ((d0 + d1) + d2) * eet;
        p = (t < mylen) ? pn : p;
        if ((t & 7) == 0) {
          // group-uniform renorm by OLD p[0] (already in registers);
          // any uniform positive scale is valid — L compensates exactly.
          const float f = A0[0];
          p *= __builtin_amdgcn_rcpf(f);
          L += __logf(f);
        }
        sb[jloc] = p;  // state for step t+1
      }
      const float w = p * __expf(endT[jloc]);
      float res = 0.f;
#pragma unroll
      for (int gg = 0; gg < 3; ++gg) {
        if (bblk * 3 + gg < B_) {
          float tot = 0.f;
#pragma unroll
          for (int i = 0; i < K_; ++i) tot += rdl(w, gg * K_ + i);
          res += rdl(L, gg * K_) + __logf(tot);
        }
      }
      if (lane == 0) atomicAdd(out_loss, res);  // +den
    } else {
      // ---------------- Viterbi ----------------
      float tr[21];  // trans[:, jloc] + 2048 straight (no rotation)
#pragma unroll
      for (int i = 0; i < K_; ++i) tr[i] = trans[i * K_ + jloc] + 2048.0f;
      float sc = startT[jloc] + em0;
      sb[jloc] = sc;
      float vt1 = fc[((size_t)1 * B_ + batch) * K_ + jloc];
      float vt2 = fc[((size_t)2 * B_ + batch) * K_ + jloc];

      for (int t = 1; t < T_; ++t) {
        const v4f A0 = sv[0], A1 = sv[1], A2 = sv[2], A3 = sv[3], A4 = sv[4];
        const float A5 = sb[20];
        const float emt = vt1;
        vt1 = vt2;
        const int tn = (t + 2 < T_) ? t + 2 : T_ - 1;
        vt2 = fc[((size_t)tn * B_ + batch) * K_ + jloc];

        int k0 = 0, k1 = 0, k2 = 0;  // keys positive (score+2048 > 0)
        // key = (float bits & ~31) | (20 - i): larger key <=> smaller prev
        // tag on ties (matches jnp.argmax first-max). v_and_or_b32 fusable.
#define VT(i, V)                                                             \
        {                                                                    \
          const float c = (V) + tr[i];                                       \
          const int kk = (__float_as_int(c) & 0xFFFFFFE0) | (20 - (i));      \
          if ((i) % 3 == 0) k0 = k0 > kk ? k0 : kk;                          \
          else if ((i) % 3 == 1) k1 = k1 > kk ? k1 : kk;                     \
          else k2 = k2 > kk ? k2 : kk;                                       \
        }
        VT(0, A0[0]) VT(1, A0[1]) VT(2, A0[2]) VT(3, A0[3])
        VT(4, A1[0]) VT(5, A1[1]) VT(6, A1[2]) VT(7, A1[3])
        VT(8, A2[0]) VT(9, A2[1]) VT(10, A2[2]) VT(11, A2[3])
        VT(12, A3[0]) VT(13, A3[1]) VT(14, A3[2]) VT(15, A3[3])
        VT(16, A4[0]) VT(17, A4[1]) VT(18, A4[2]) VT(19, A4[3])
        VT(20, A5)
#undef VT
        int km = k0 > k1 ? k0 : k1;
        km = km > k2 ? km : k2;
        const float nxt = __int_as_float(km & 0xFFFFFFE0) - 2048.0f + emt;
        const bool m = t < mylen;
        sc = m ? nxt : sc;
        sb[jloc] = sc;  // state for step t+1
        const int pw = m ? (20 - (km & 31)) : jloc;  // identity when frozen
        if (lane < 63) bp[t * 66 + g * 22 + jloc] = (unsigned short)pw;
      }
      __syncthreads();

      // final argmax per group (tie-break: smallest tag)
      const float finb = sc + endT[jloc] + 2048.0f;
      const int myk = (__float_as_int(finb) & 0xFFFFFFE0) | (20 - jloc);
      int last0 = 0, last1 = 0, last2 = 0;
#pragma unroll
      for (int gg = 0; gg < 3; ++gg) {
        int km = 0;
#pragma unroll
        for (int i = 0; i < K_; ++i) {
          const int ki = __builtin_amdgcn_readlane(myk, gg * K_ + i);
          km = km > ki ? km : ki;
        }
        const int lt = 20 - (km & 31);
        if (gg == 0) last0 = lt;
        else if (gg == 1) last1 = lt;
        else last2 = lt;
      }

      // skip tables (parallel over lanes)
      for (int i = lane; i < 127 * 63; i += 64) {
        const int v = i / 63;
        const int rem = i - v * 63;
        const int gg = rem / 21, j = rem - (rem / 21) * 21;
        h2[v * 66 + gg * 22 + j] = (unsigned char)
            bp[(2 * v + 1) * 66 + gg * 22 + bp[(2 * v + 2) * 66 + gg * 22 + j]];
      }
      __syncthreads();
      for (int i = lane; i < 63 * 63; i += 64) {
        const int w = i / 63;
        const int rem = i - w * 63;
        const int gg = rem / 21, j = rem - (rem / 21) * 21;
        h4[w * 66 + gg * 22 + j] =
            h2[(2 * w) * 66 + gg * 22 + h2[(2 * w + 1) * 66 + gg * 22 + j]];
      }
      __syncthreads();

      // 3 parallel serial chases (lane == group)
      if (lane < 3 && bblk * 3 + lane < B_) {
        int c = (lane == 0) ? last0 : (lane == 1) ? last1 : last2;
        cur[lane * 256 + 255] = (unsigned char)c;
        c = bp[255 * 66 + lane * 22 + c];
        cur[lane * 256 + 254] = (unsigned char)c;
        c = h2[126 * 66 + lane * 22 + c];
        cur[lane * 256 + 252] = (unsigned char)c;
        for (int w = 62; w >= 0; --w) {
          c = h4[w * 66 + lane * 22 + c];
          cur[lane * 256 + 4 * w] = (unsigned char)c;
        }
      }
      __syncthreads();
      for (int i = lane; i < 63 * 3; i += 64) {  // t = 2 mod 4
        const int gg = i / 63, ii = i - (i / 63) * 63;
        const int t = 2 + 4 * ii;
        cur[gg * 256 + t] =
            h2[(t >> 1) * 66 + gg * 22 + cur[gg * 256 + t + 2]];
      }
      __syncthreads();
      for (int i = lane; i < 127 * 3; i += 64) {  // odd t
        const int gg = i / 127, ii = i - (i / 127) * 127;
        const int t = 1 + 2 * ii;
        cur[gg * 256 + t] = (unsigned char)
            bp[(t + 1) * 66 + gg * 22 + cur[gg * 256 + t + 1]];
      }
      __syncthreads();
      for (int i = lane; i < 3 * 256; i += 64) {
        const int gg = i >> 8, t = i & 255;
        const int bb = bblk * 3 + gg;
        const int lg = (gg == 0) ? len0 : (gg == 1) ? len1 : len2;
        if (bb < B_)
          out_tags[t * B_ + bb] = (t < lg) ? (float)cur[gg * 256 + t] : 0.f;
      }
    }
  } else {
    // ---------------- numerator ----------------
    const int b = blk - 2 * NB3;
    float contrib = 0.f;
#pragma unroll
    for (int q = 0; q < 4; ++q) {
      const int t = lane * 4 + q;
      const int tg = tags[t * B_ + b];
      const size_t ro = ((size_t)t * B_ + b) * K_;
      if (t == 0) {
        contrib += startT[tg] + fc[ro + tg];
      } else if (tg != 0) {
        const int pg = tags[(t - 1) * B_ + b];
        contrib += trans[pg * K_ + tg] + fc[ro + tg];
      }
      const bool isLast =
          (tg != 0) && (t == T_ - 1 || tags[(t + 1) * B_ + b] == 0);
      if (isLast) contrib += endT[tg];
    }
#pragma unroll
    for (int off = 32; off > 0; off >>= 1)
      contrib += __shfl_down(contrib, off, 64);
    if (lane == 0) atomicAdd(out_loss, -contrib);  // -num
  }
}

extern "C" void kernel_launch(void* const* d_in, const int* in_sizes, int n_in,
                              void* d_out, int out_size, void* d_ws,
                              size_t ws_size, hipStream_t stream) {
  const float* A = (const float*)d_in[0];
  const int* tags = (const int*)d_in[1];
  const float* W = (const float*)d_in[2];
  const float* bias = (const float*)d_in[3];
  const float* startT = (const float*)d_in[4];
  const float* endT = (const float*)d_in[5];
  const float* trans = (const float*)d_in[6];

  float* out_tags = (float*)d_out;
  float* out_loss = (float*)d_out + (size_t)T_ * B_;
  float* fc = (float*)d_ws;  // [t*B+b][21] f32, 2.75 MB

  hipMemsetAsync(out_loss, 0, sizeof(float), stream);
  fc_kernel<<<512, 256, 0, stream>>>(A, W, bias, fc);
  scan_kernel<<<2 * NB3 + B_, 64, 0, stream>>>(fc, tags, startT, endT, trans,
                                               out_tags, out_loss);
}

// Round 2
// 277.831 us; speedup vs baseline: 1.1403x; 1.0729x over previous
//
#include <hip/hip_runtime.h>
#include <math.h>

#define T_ 256
#define B_ 128
#define D_ 1024
#define K_ 21
#define NB3 43  // ceil(B_/3) wave-blocks for each scan flavor

typedef short v8s __attribute__((ext_vector_type(8)));
typedef float v4f __attribute__((ext_vector_type(4)));

__device__ __forceinline__ short bf16rne(float f) {
  unsigned u = __float_as_uint(f);
  u += 0x7FFFu + ((u >> 16) & 1u);  // round-nearest-even
  return (short)(u >> 16);
}
__device__ __forceinline__ float rdl(float v, int l) {
  return __int_as_float(__builtin_amdgcn_readlane(__float_as_int(v), l));
}

// ---------------------------------------------------------------------------
// Kernel 1: FC as bf16 MFMA GEMM (unchanged). Block = 256 thr (4 waves);
// wave wv owns k-chunk [wv*256, +256) for rows [blockIdx.x*64, +64).
// ---------------------------------------------------------------------------
__global__ __launch_bounds__(256) void fc_kernel(
    const float* __restrict__ A, const float* __restrict__ W,
    const float* __restrict__ bias, float* __restrict__ fc) {
  __shared__ float red[3][64][22];
  const int lane = threadIdx.x & 63;
  const int wv = threadIdx.x >> 6;
  const int m15 = lane & 15, g4 = lane >> 4;
  const int rowbase = blockIdx.x * 64;
  const int kc = wv * 256;
  const int n1 = 16 + m15;

  v8s bf[8][2];
#pragma unroll
  for (int s = 0; s < 8; ++s) {
    const float* Wp = W + (size_t)(kc + 32 * s + 8 * g4) * K_;
#pragma unroll
    for (int j = 0; j < 8; ++j) bf[s][0][j] = bf16rne(Wp[j * K_ + m15]);
    if (n1 < K_) {
#pragma unroll
      for (int j = 0; j < 8; ++j) bf[s][1][j] = bf16rne(Wp[j * K_ + n1]);
    } else {
#pragma unroll
      for (int j = 0; j < 8; ++j) bf[s][1][j] = 0;
    }
  }

  v4f acc[4][2];
#pragma unroll
  for (int m = 0; m < 4; ++m) {
    acc[m][0] = (v4f)(0.f);
    acc[m][1] = (v4f)(0.f);
  }

#pragma unroll
  for (int s = 0; s < 8; ++s) {
    v8s av[4];
#pragma unroll
    for (int m = 0; m < 4; ++m) {
      const float* Ap =
          A + (size_t)(rowbase + 16 * m + m15) * D_ + kc + 32 * s + 8 * g4;
      const float4 x = *(const float4*)Ap;
      const float4 y = *(const float4*)(Ap + 4);
      av[m][0] = bf16rne(x.x); av[m][1] = bf16rne(x.y);
      av[m][2] = bf16rne(x.z); av[m][3] = bf16rne(x.w);
      av[m][4] = bf16rne(y.x); av[m][5] = bf16rne(y.y);
      av[m][6] = bf16rne(y.z); av[m][7] = bf16rne(y.w);
    }
#pragma unroll
    for (int m = 0; m < 4; ++m) {
      acc[m][0] = __builtin_amdgcn_mfma_f32_16x16x32_bf16(av[m], bf[s][0],
                                                          acc[m][0], 0, 0, 0);
      acc[m][1] = __builtin_amdgcn_mfma_f32_16x16x32_bf16(av[m], bf[s][1],
                                                          acc[m][1], 0, 0, 0);
    }
  }

  if (wv > 0) {
#pragma unroll
    for (int m = 0; m < 4; ++m)
#pragma unroll
      for (int ri = 0; ri < 4; ++ri) {
        const int rl = 16 * m + 4 * g4 + ri;
        red[wv - 1][rl][m15] = acc[m][0][ri];
        if (n1 < K_) red[wv - 1][rl][n1] = acc[m][1][ri];
      }
  }
  __syncthreads();
  if (wv == 0) {
    const float b0 = bias[m15];
    const float b1 = (n1 < K_) ? bias[n1] : 0.f;
#pragma unroll
    for (int m = 0; m < 4; ++m)
#pragma unroll
      for (int ri = 0; ri < 4; ++ri) {
        const int rl = 16 * m + 4 * g4 + ri;
        float* o = fc + (size_t)(rowbase + rl) * K_;
        o[m15] = acc[m][0][ri] + red[0][rl][m15] + red[1][rl][m15] +
                 red[2][rl][m15] + b0;
        if (n1 < K_)
          o[n1] = acc[m][1][ri] + red[0][rl][n1] + red[1][rl][n1] +
                  red[2][rl][n1] + b1;
      }
  }
}

// ---------------------------------------------------------------------------
// Kernel 2: sequential scans. 3 batches per wave, lane = g*21 + jloc.
// v2: per-step all-gather through an LDS state vector (1 ds_write_b32 +
//     5 ds_read_b128 + 1 ds_read_b32, per-wave in-order => no barrier).
// v3: emission prefetch deepened to distance 4 via a rotating 4-register
//     pipeline (manually unrolled x4, static rotation). fc lives in L3
//     (~600 cy); the old distance-1 prefetch stalled ~500 cy/step at the
//     s_waitcnt vmcnt before the exp/move. 4 slots x ~300 cy/iter covers
//     the latency.  Loads past T-1 clamp (values dead).
// Blocks [0,43): forward; [43,86): Viterbi; [86,214): numerator.
// ---------------------------------------------------------------------------
__global__ __launch_bounds__(64) void scan_kernel(
    const float* __restrict__ fc, const int* __restrict__ tags,
    const float* __restrict__ startT, const float* __restrict__ endT,
    const float* __restrict__ trans, float* __restrict__ out_tags,
    float* __restrict__ out_loss) {
  __shared__ unsigned short bp[256 * 66];  // bp[t][g][tag], stride 66/22
  __shared__ unsigned char h2[127 * 66];   // tag@2v   <- tag@(2v+2)
  __shared__ unsigned char h4[63 * 66];    // tag@4w   <- tag@(4w+4)
  __shared__ unsigned char cur[3 * 256];
  __shared__ v4f statev[18];               // 3 groups x 24 floats (21 + pad)

  const int lane = threadIdx.x;
  const int blk = blockIdx.x;

  if (blk < 2 * NB3) {
    const bool fwd = blk < NB3;
    const int bblk = fwd ? blk : blk - NB3;
    int g = lane / 21;
    if (g > 2) g = 2;
    int jloc = lane - g * 21;
    if (jloc > 20) jloc = 20;
    int batch = bblk * 3 + g;
    if (batch >= B_) batch = B_ - 1;

    // lengths per group (uniform, via ballots); mask[t] == (t < len)
    int len0 = 0, len1 = 0, len2 = 0;
#pragma unroll
    for (int q = 0; q < 4; ++q) {
      const int t = q * 64 + lane;
      int b0 = bblk * 3, b1 = bblk * 3 + 1, b2 = bblk * 3 + 2;
      if (b1 >= B_) b1 = B_ - 1;
      if (b2 >= B_) b2 = B_ - 1;
      len0 += __popcll(__ballot(tags[t * B_ + b0] != 0));
      len1 += __popcll(__ballot(tags[t * B_ + b1] != 0));
      len2 += __popcll(__ballot(tags[t * B_ + b2] != 0));
    }
    const int mylen = (g == 0) ? len0 : (g == 1) ? len1 : len2;

    float* sb = (float*)statev + g * 24;   // this group's state (21 floats)
    const v4f* sv = (const v4f*)sb;        // 16B-aligned (24 floats = 96B)

#define FCAT(t) fc[((size_t)(t) * B_ + batch) * K_ + jloc]
    const float em0 = FCAT(0);

    if (fwd) {
      // ---------------- forward / denominator (linear domain) ------------
      float ec[21];  // exp(trans[:, jloc]) straight (no rotation)
#pragma unroll
      for (int i = 0; i < K_; ++i) ec[i] = __expf(trans[i * K_ + jloc]);
      float p = __expf(startT[jloc] + em0);
      sb[jloc] = p;  // lane 63 duplicates lane 62's write (same value)
      float L = 0.f;
      // rotating emission pipeline: entering iter t, slots = fc[t+1..t+4],
      // ee = exp(fc[t]).
      float sA = FCAT(2), sB = FCAT(3), sC = FCAT(4), sD = FCAT(5);
      float ee = __expf(FCAT(1));

#define FWD_STEP(t, RA, RB, RC, RD)                                          \
      {                                                                      \
        const v4f A0 = sv[0], A1 = sv[1], A2 = sv[2], A3 = sv[3],            \
                  A4 = sv[4];                                                \
        const float A5 = sb[20];                                             \
        const float eet = ee;                                                \
        ee = __expf(RA); /* RA = fc[t+1], loaded 4 iters ago */              \
        {                                                                    \
          const int tn = ((t) + 5 < T_) ? (t) + 5 : T_ - 1;                  \
          RA = FCAT(tn); /* refill consumed slot */                          \
        }                                                                    \
        float d0 = A0[0] * ec[0], d1 = A0[1] * ec[1], d2 = A0[2] * ec[2];    \
        d0 = fmaf(A0[3], ec[3], d0); d1 = fmaf(A1[0], ec[4], d1);            \
        d2 = fmaf(A1[1], ec[5], d2);                                         \
        d0 = fmaf(A1[2], ec[6], d0); d1 = fmaf(A1[3], ec[7], d1);            \
        d2 = fmaf(A2[0], ec[8], d2);                                         \
        d0 = fmaf(A2[1], ec[9], d0); d1 = fmaf(A2[2], ec[10], d1);           \
        d2 = fmaf(A2[3], ec[11], d2);                                        \
        d0 = fmaf(A3[0], ec[12], d0); d1 = fmaf(A3[1], ec[13], d1);          \
        d2 = fmaf(A3[2], ec[14], d2);                                        \
        d0 = fmaf(A3[3], ec[15], d0); d1 = fmaf(A4[0], ec[16], d1);          \
        d2 = fmaf(A4[1], ec[17], d2);                                        \
        d0 = fmaf(A4[2], ec[18], d0); d1 = fmaf(A4[3], ec[19], d1);          \
        d2 = fmaf(A5, ec[20], d2);                                           \
        const float pn = ((d0 + d1) + d2) * eet;                             \
        p = ((t) < mylen) ? pn : p;                                          \
        if (((t) & 7) == 0) {                                                \
          /* group-uniform renorm by OLD p[0] (in registers) */              \
          const float f = A0[0];                                             \
          p *= __builtin_amdgcn_rcpf(f);                                     \
          L += __logf(f);                                                    \
        }                                                                    \
        sb[jloc] = p; /* state for step t+1 */                               \
      }

      for (int t = 1; t + 3 <= 252; t += 4) {
        FWD_STEP(t + 0, sA, sB, sC, sD)
        FWD_STEP(t + 1, sB, sC, sD, sA)
        FWD_STEP(t + 2, sC, sD, sA, sB)
        FWD_STEP(t + 3, sD, sA, sB, sC)
      }
      FWD_STEP(253, sA, sB, sC, sD)
      FWD_STEP(254, sB, sC, sD, sA)
      FWD_STEP(255, sC, sD, sA, sB)
#undef FWD_STEP

      const float w = p * __expf(endT[jloc]);
      float res = 0.f;
#pragma unroll
      for (int gg = 0; gg < 3; ++gg) {
        if (bblk * 3 + gg < B_) {
          float tot = 0.f;
#pragma unroll
          for (int i = 0; i < K_; ++i) tot += rdl(w, gg * K_ + i);
          res += rdl(L, gg * K_) + __logf(tot);
        }
      }
      if (lane == 0) atomicAdd(out_loss, res);  // +den
    } else {
      // ---------------- Viterbi ----------------
      float tr[21];  // trans[:, jloc] + 2048 straight (no rotation)
#pragma unroll
      for (int i = 0; i < K_; ++i) tr[i] = trans[i * K_ + jloc] + 2048.0f;
      float sc = startT[jloc] + em0;
      sb[jloc] = sc;
      // rotating emission pipeline: entering iter t, slots = fc[t..t+3]
      float sA = FCAT(1), sB = FCAT(2), sC = FCAT(3), sD = FCAT(4);

#define VIT_STEP(t, RA, RB, RC, RD)                                          \
      {                                                                      \
        const v4f A0 = sv[0], A1 = sv[1], A2 = sv[2], A3 = sv[3],            \
                  A4 = sv[4];                                                \
        const float A5 = sb[20];                                             \
        const float emt = RA; /* fc[t], loaded 4 iters ago */                \
        {                                                                    \
          const int tn = ((t) + 4 < T_) ? (t) + 4 : T_ - 1;                  \
          RA = FCAT(tn);                                                     \
        }                                                                    \
        int k0 = 0, k1 = 0, k2 = 0; /* keys positive (score+2048 > 0) */     \
        /* key = (bits & ~31) | (20-i): larger key <=> smaller prev tag */   \
        const float c0 = A0[0] + tr[0];                                      \
        k0 = (__float_as_int(c0) & 0xFFFFFFE0) | 20;                         \
        const float c1 = A0[1] + tr[1];                                      \
        k1 = (__float_as_int(c1) & 0xFFFFFFE0) | 19;                         \
        const float c2 = A0[2] + tr[2];                                      \
        k2 = (__float_as_int(c2) & 0xFFFFFFE0) | 18;                         \
        {                                                                    \
          const float c = A0[3] + tr[3];                                     \
          const int kk = (__float_as_int(c) & 0xFFFFFFE0) | 17;              \
          k0 = k0 > kk ? k0 : kk;                                            \
        }                                                                    \
        {                                                                    \
          const float c = A1[0] + tr[4];                                     \
          const int kk = (__float_as_int(c) & 0xFFFFFFE0) | 16;              \
          k1 = k1 > kk ? k1 : kk;                                            \
        }                                                                    \
        {                                                                    \
          const float c = A1[1] + tr[5];                                     \
          const int kk = (__float_as_int(c) & 0xFFFFFFE0) | 15;              \
          k2 = k2 > kk ? k2 : kk;                                            \
        }                                                                    \
        {                                                                    \
          const float c = A1[2] + tr[6];                                     \
          const int kk = (__float_as_int(c) & 0xFFFFFFE0) | 14;              \
          k0 = k0 > kk ? k0 : kk;                                            \
        }                                                                    \
        {                                                                    \
          const float c = A1[3] + tr[7];                                     \
          const int kk = (__float_as_int(c) & 0xFFFFFFE0) | 13;              \
          k1 = k1 > kk ? k1 : kk;                                            \
        }                                                                    \
        {                                                                    \
          const float c = A2[0] + tr[8];                                     \
          const int kk = (__float_as_int(c) & 0xFFFFFFE0) | 12;              \
          k2 = k2 > kk ? k2 : kk;                                            \
        }                                                                    \
        {                                                                    \
          const float c = A2[1] + tr[9];                                     \
          const int kk = (__float_as_int(c) & 0xFFFFFFE0) | 11;              \
          k0 = k0 > kk ? k0 : kk;                                            \
        }                                                                    \
        {                                                                    \
          const float c = A2[2] + tr[10];                                    \
          const int kk = (__float_as_int(c) & 0xFFFFFFE0) | 10;              \
          k1 = k1 > kk ? k1 : kk;                                            \
        }                                                                    \
        {                                                                    \
          const float c = A2[3] + tr[11];                                    \
          const int kk = (__float_as_int(c) & 0xFFFFFFE0) | 9;               \
          k2 = k2 > kk ? k2 : kk;                                            \
        }                                                                    \
        {                                                                    \
          const float c = A3[0] + tr[12];                                    \
          const int kk = (__float_as_int(c) & 0xFFFFFFE0) | 8;               \
          k0 = k0 > kk ? k0 : kk;                                            \
        }                                                                    \
        {                                                                    \
          const float c = A3[1] + tr[13];                                    \
          const int kk = (__float_as_int(c) & 0xFFFFFFE0) | 7;               \
          k1 = k1 > kk ? k1 : kk;                                            \
        }                                                                    \
        {                                                                    \
          const float c = A3[2] + tr[14];                                    \
          const int kk = (__float_as_int(c) & 0xFFFFFFE0) | 6;               \
          k2 = k2 > kk ? k2 : kk;                                            \
        }                                                                    \
        {                                                                    \
          const float c = A3[3] + tr[15];                                    \
          const int kk = (__float_as_int(c) & 0xFFFFFFE0) | 5;               \
          k0 = k0 > kk ? k0 : kk;                                            \
        }                                                                    \
        {                                                                    \
          const float c = A4[0] + tr[16];                                    \
          const int kk = (__float_as_int(c) & 0xFFFFFFE0) | 4;               \
          k1 = k1 > kk ? k1 : kk;                                            \
        }                                                                    \
        {                                                                    \
          const float c = A4[1] + tr[17];                                    \
          const int kk = (__float_as_int(c) & 0xFFFFFFE0) | 3;               \
          k2 = k2 > kk ? k2 : kk;                                            \
        }                                                                    \
        {                                                                    \
          const float c = A4[2] + tr[18];                                    \
          const int kk = (__float_as_int(c) & 0xFFFFFFE0) | 2;               \
          k0 = k0 > kk ? k0 : kk;                                            \
        }                                                                    \
        {                                                                    \
          const float c = A4[3] + tr[19];                                    \
          const int kk = (__float_as_int(c) & 0xFFFFFFE0) | 1;               \
          k1 = k1 > kk ? k1 : kk;                                            \
        }                                                                    \
        {                                                                    \
          const float c = A5 + tr[20];                                       \
          const int kk = (__float_as_int(c) & 0xFFFFFFE0) | 0;               \
          k2 = k2 > kk ? k2 : kk;                                            \
        }                                                                    \
        int km = k0 > k1 ? k0 : k1;                                          \
        km = km > k2 ? km : k2;                                              \
        const float nxt = __int_as_float(km & 0xFFFFFFE0) - 2048.0f + emt;   \
        const bool m = (t) < mylen;                                          \
        sc = m ? nxt : sc;                                                   \
        sb[jloc] = sc; /* state for step t+1 */                              \
        const int pw = m ? (20 - (km & 31)) : jloc;                          \
        if (lane < 63) bp[(t) * 66 + g * 22 + jloc] = (unsigned short)pw;    \
      }

      for (int t = 1; t + 3 <= 252; t += 4) {
        VIT_STEP(t + 0, sA, sB, sC, sD)
        VIT_STEP(t + 1, sB, sC, sD, sA)
        VIT_STEP(t + 2, sC, sD, sA, sB)
        VIT_STEP(t + 3, sD, sA, sB, sC)
      }
      VIT_STEP(253, sA, sB, sC, sD)
      VIT_STEP(254, sB, sC, sD, sA)
      VIT_STEP(255, sC, sD, sA, sB)
#undef VIT_STEP
      __syncthreads();

      // final argmax per group (tie-break: smallest tag)
      const float finb = sc + endT[jloc] + 2048.0f;
      const int myk = (__float_as_int(finb) & 0xFFFFFFE0) | (20 - jloc);
      int last0 = 0, last1 = 0, last2 = 0;
#pragma unroll
      for (int gg = 0; gg < 3; ++gg) {
        int km = 0;
#pragma unroll
        for (int i = 0; i < K_; ++i) {
          const int ki = __builtin_amdgcn_readlane(myk, gg * K_ + i);
          km = km > ki ? km : ki;
        }
        const int lt = 20 - (km & 31);
        if (gg == 0) last0 = lt;
        else if (gg == 1) last1 = lt;
        else last2 = lt;
      }

      // skip tables (parallel over lanes)
      for (int i = lane; i < 127 * 63; i += 64) {
        const int v = i / 63;
        const int rem = i - v * 63;
        const int gg = rem / 21, j = rem - (rem / 21) * 21;
        h2[v * 66 + gg * 22 + j] = (unsigned char)
            bp[(2 * v + 1) * 66 + gg * 22 + bp[(2 * v + 2) * 66 + gg * 22 + j]];
      }
      __syncthreads();
      for (int i = lane; i < 63 * 63; i += 64) {
        const int w = i / 63;
        const int rem = i - w * 63;
        const int gg = rem / 21, j = rem - (rem / 21) * 21;
        h4[w * 66 + gg * 22 + j] =
            h2[(2 * w) * 66 + gg * 22 + h2[(2 * w + 1) * 66 + gg * 22 + j]];
      }
      __syncthreads();

      // 3 parallel serial chases (lane == group)
      if (lane < 3 && bblk * 3 + lane < B_) {
        int c = (lane == 0) ? last0 : (lane == 1) ? last1 : last2;
        cur[lane * 256 + 255] = (unsigned char)c;
        c = bp[255 * 66 + lane * 22 + c];
        cur[lane * 256 + 254] = (unsigned char)c;
        c = h2[126 * 66 + lane * 22 + c];
        cur[lane * 256 + 252] = (unsigned char)c;
        for (int w = 62; w >= 0; --w) {
          c = h4[w * 66 + lane * 22 + c];
          cur[lane * 256 + 4 * w] = (unsigned char)c;
        }
      }
      __syncthreads();
      for (int i = lane; i < 63 * 3; i += 64) {  // t = 2 mod 4
        const int gg = i / 63, ii = i - (i / 63) * 63;
        const int t = 2 + 4 * ii;
        cur[gg * 256 + t] =
            h2[(t >> 1) * 66 + gg * 22 + cur[gg * 256 + t + 2]];
      }
      __syncthreads();
      for (int i = lane; i < 127 * 3; i += 64) {  // odd t
        const int gg = i / 127, ii = i - (i / 127) * 127;
        const int t = 1 + 2 * ii;
        cur[gg * 256 + t] = (unsigned char)
            bp[(t + 1) * 66 + gg * 22 + cur[gg * 256 + t + 1]];
      }
      __syncthreads();
      for (int i = lane; i < 3 * 256; i += 64) {
        const int gg = i >> 8, t = i & 255;
        const int bb = bblk * 3 + gg;
        const int lg = (gg == 0) ? len0 : (gg == 1) ? len1 : len2;
        if (bb < B_)
          out_tags[t * B_ + bb] = (t < lg) ? (float)cur[gg * 256 + t] : 0.f;
      }
    }
#undef FCAT
  } else {
    // ---------------- numerator ----------------
    const int b = blk - 2 * NB3;
    float contrib = 0.f;
#pragma unroll
    for (int q = 0; q < 4; ++q) {
      const int t = lane * 4 + q;
      const int tg = tags[t * B_ + b];
      const size_t ro = ((size_t)t * B_ + b) * K_;
      if (t == 0) {
        contrib += startT[tg] + fc[ro + tg];
      } else if (tg != 0) {
        const int pg = tags[(t - 1) * B_ + b];
        contrib += trans[pg * K_ + tg] + fc[ro + tg];
      }
      const bool isLast =
          (tg != 0) && (t == T_ - 1 || tags[(t + 1) * B_ + b] == 0);
      if (isLast) contrib += endT[tg];
    }
#pragma unroll
    for (int off = 32; off > 0; off >>= 1)
      contrib += __shfl_down(contrib, off, 64);
    if (lane == 0) atomicAdd(out_loss, -contrib);  // -num
  }
}

extern "C" void kernel_launch(void* const* d_in, const int* in_sizes, int n_in,
                              void* d_out, int out_size, void* d_ws,
                              size_t ws_size, hipStream_t stream) {
  const float* A = (const float*)d_in[0];
  const int* tags = (const int*)d_in[1];
  const float* W = (const float*)d_in[2];
  const float* bias = (const float*)d_in[3];
  const float* startT = (const float*)d_in[4];
  const float* endT = (const float*)d_in[5];
  const float* trans = (const float*)d_in[6];

  float* out_tags = (float*)d_out;
  float* out_loss = (float*)d_out + (size_t)T_ * B_;
  float* fc = (float*)d_ws;  // [t*B+b][21] f32, 2.75 MB

  hipMemsetAsync(out_loss, 0, sizeof(float), stream);
  fc_kernel<<<512, 256, 0, stream>>>(A, W, bias, fc);
  scan_kernel<<<2 * NB3 + B_, 64, 0, stream>>>(fc, tags, startT, endT, trans,
                                               out_tags, out_loss);
}